// Round 1
// 215.651 us; speedup vs baseline: 1.0336x; 1.0336x over previous
//
#include <hip/hip_runtime.h>

typedef float  f32x4  __attribute__((ext_vector_type(4)));
typedef float  f32x2  __attribute__((ext_vector_type(2)));
typedef short  bf16x8 __attribute__((ext_vector_type(8)));

#define TWOLOG2E   2.8853900817779268f
#define NLOG2E    -1.4426950408889634f
#define NTWOLOG2E -2.8853900817779268f

__device__ __forceinline__ unsigned short f2b(float f) {      // fp32 -> bf16 RNE
    unsigned int u = __builtin_bit_cast(unsigned int, f);
    u += 0x7fffu + ((u >> 16) & 1u);
    return (unsigned short)(u >> 16);
}
__device__ __forceinline__ float b2f(unsigned short s) {
    unsigned int u = ((unsigned int)s) << 16;
    return __builtin_bit_cast(float, u);
}
__device__ __forceinline__ unsigned int pk2(float lo, float hi) {
#if __has_builtin(__builtin_amdgcn_cvt_pk_bf16_f32)
    typedef __bf16 bf16x2 __attribute__((ext_vector_type(2)));
    bf16x2 p = __builtin_amdgcn_cvt_pk_bf16_f32(lo, hi);
    return __builtin_bit_cast(unsigned int, p);
#else
    return (unsigned int)f2b(lo) | ((unsigned int)f2b(hi) << 16);
#endif
}
__device__ __forceinline__ float frcp(float x) { return __builtin_amdgcn_rcpf(x); }
__device__ __forceinline__ float fex2(float x) { return __builtin_amdgcn_exp2f(x); }

// R14: packed-FP32 epilogue. Same pipelined structure as R9 (block=256=4 waves,
// wave l owns layer l, 2-timestep super-steps, 35 barriers, B-frags in VGPR/AGPR
// pre-scaled by -log2e / -2log2e, bias in MFMA C operand). Change: the per-unit
// scalar epilogue (~13 f32 ops) is rewritten on <2 x float> pairing the two
// hf-halves so the backend emits v_pk_{add,mul,fma}_f32 (double-pumped fp32,
// 2 ops/instr). exp2/rcp remain scalar per half (no packed trans) -> results
// bit-identical. Also hoists bias C-quads (cbq) and per-lane LDS offsets.
// Epilogue math per unit (unchanged): 5 exp2 + 2 rcp, merged-rcp denominator:
//   p1=(1+ei)(1+eg); cn' = [cp*p1 - 2log2e(1-eg)(1+ef)] * rcp(p1*(1+ef))
//   (cp = -2log2e*c pre-scaled);  ec = exp2(cp);  h = (1-ec)*rcp((1+eo)(1+ec))
// Structural notes (measured, R7-R13): more waves/SIMD, spin-chaining, and
// fully-decoupled 1-wave/SIMD variants all regress; ~21% residual idle is
// pipeline fill/drain + barrier convoy and resisted 4 attacks.
__global__ __launch_bounds__(256, 2)
void lstm_mfma(const float* __restrict__ xg,  const float* __restrict__ Wih0,
               const float* __restrict__ Wih, const float* __restrict__ Whh,
               const float* __restrict__ bih, const float* __restrict__ bhh,
               const float* __restrict__ Wlin,const float* __restrict__ blin,
               float* __restrict__ out) {
    __shared__ short        hb[16 * 1280] __attribute__((aligned(16))); // [l][p][slot][32row*40]
    __shared__ unsigned int xb[64 * 32];                                // [t][row] 2xbf16

    const int tid  = threadIdx.x;
    const int wv   = __builtin_amdgcn_readfirstlane(tid >> 6);  // layer id, uniform
    const int lane = tid & 63;
    const int m    = lane & 15;    // A-row / D-col index
    const int q    = lane >> 4;    // quad
    const int row0 = blockIdx.x * 32;

    // zero all h buffers (first reads must see 0)
    for (int i = tid; i < 10240; i += 256) ((unsigned int*)hb)[i] = 0u;

    // stage x -> LDS bf16 [t][row]
    for (int i = tid; i < 2048; i += 256) {
        int r = i >> 6, t = i & 63;
        float x0 = xg[(size_t)(row0 + r) * 192 + t];
        float x1 = xg[(size_t)(row0 + r) * 192 + 64 + t];
        xb[t * 32 + r] = pk2(x0, x1);
    }

    // ---- one-time gather of B-frags + bias (negated scales) ----
    // tile g: gate T=g>>1 of unit 2m+(g&1); rowG = T*32 + 2m + (g&1).
    bf16x8 bfr[8][2];
    float  bv[8];
#pragma unroll
    for (int g = 0; g < 8; ++g) {
        const int   T    = g >> 1;
        const int   rowG = T * 32 + 2 * m + (g & 1);
        const float sc   = (T == 2) ? NTWOLOG2E : NLOG2E;
        bv[g] = (bih[wv * 128 + rowG] + bhh[wv * 128 + rowG]) * sc;
#pragma unroll
        for (int c = 0; c < 2; ++c) {
            const int k0 = c * 32 + q * 8;
            float w[8];
            if (wv == 0) {
                if (c == 0) {
#pragma unroll
                    for (int jj = 0; jj < 8; ++jj) w[jj] = 0.0f;
                    if (q == 0) { w[0] = Wih0[rowG * 2]; w[1] = Wih0[rowG * 2 + 1]; }
                } else {
                    const float* src = Whh + rowG * 32 + (k0 - 32);
#pragma unroll
                    for (int jj = 0; jj < 8; ++jj) w[jj] = src[jj];
                }
            } else {
                const float* src = (c == 0) ? (Wih + (wv - 1) * 4096 + rowG * 32 + k0)
                                            : (Whh + wv * 4096 + rowG * 32 + (k0 - 32));
#pragma unroll
                for (int jj = 0; jj < 8; ++jj) w[jj] = src[jj];
            }
            bf16x8 fr;
#pragma unroll
            for (int jj = 0; jj < 8; ++jj) fr[jj] = (short)f2b(w[jj] * sc);
            bfr[g][c] = fr;
        }
    }

    // hoisted bias C-operand quads (persistent; avoids per-MFMA re-splat)
    f32x4 cbq[8];
#pragma unroll
    for (int g = 0; g < 8; ++g) {
        f32x4 c4 = {bv[g], bv[g], bv[g], bv[g]};
        cbq[g] = c4;
    }

    f32x2 cp2[2][4];   // scaled cell state -2log2e*c: [tt][r], .x=hf0 .y=hf1
#pragma unroll
    for (int tt = 0; tt < 2; ++tt)
#pragma unroll
        for (int r = 0; r < 4; ++r) cp2[tt][r] = (f32x2){0.0f, 0.0f};

    // hoisted per-lane LDS offsets
    const int aoff = m * 40 + q * 8;        // short-index A-frag offset within slot
    const int woff = q * 80 + m;            // uint-index h-write offset within slot

    __syncthreads();

    // one t cell-step for all 32 rows (2 row-tiles)
    auto cell_step = [&](int t, const short* pa0, const short* pa1, short* hwr) {
        bf16x8 a0[2], a1[2];
#pragma unroll
        for (int tt = 0; tt < 2; ++tt) {
            if (wv == 0) {
                unsigned int xd = xb[t * 32 + tt * 16 + m];
                union { unsigned int u[4]; bf16x8 v; } au;
                au.u[0] = (q == 0) ? xd : 0u; au.u[1] = 0u; au.u[2] = 0u; au.u[3] = 0u;
                a0[tt] = au.v;
            } else {
                a0[tt] = *(const bf16x8*)(pa0 + aoff + tt * 640);
            }
            a1[tt] = *(const bf16x8*)(pa1 + aoff + tt * 640);
        }
#pragma unroll
        for (int tt = 0; tt < 2; ++tt) {
            f32x4 acc[8];
#pragma unroll
            for (int g = 0; g < 8; ++g) {
                acc[g] = __builtin_amdgcn_mfma_f32_16x16x32_bf16(a0[tt], bfr[g][0], cbq[g], 0, 0, 0);
                acc[g] = __builtin_amdgcn_mfma_f32_16x16x32_bf16(a1[tt], bfr[g][1], acc[g], 0, 0, 0);
            }
            const f32x2 one  = {1.0f, 1.0f};
            const f32x2 c2l  = {TWOLOG2E, TWOLOG2E};
            const f32x2 n2l  = {NTWOLOG2E, NTWOLOG2E};
#pragma unroll
            for (int r = 0; r < 4; ++r) {
                f32x2 ei = {fex2(acc[0][r]), fex2(acc[1][r])};   // e^{-a_i}, both hf halves
                f32x2 ef = {fex2(acc[2][r]), fex2(acc[3][r])};   // e^{-a_f}
                f32x2 eg = {fex2(acc[4][r]), fex2(acc[5][r])};   // e^{-2 a_g}
                f32x2 eo = {fex2(acc[6][r]), fex2(acc[7][r])};   // e^{-a_o}
                f32x2 apf = one + ef;
                f32x2 p1  = (one + ei) * (one + eg);
                f32x2 Dc  = p1 * apf;
                f32x2 R_  = {frcp(Dc.x), frcp(Dc.y)};
                f32x2 egp = __builtin_elementwise_fma(eg, c2l, n2l);  // -2log2e*(1-eg)
                f32x2 t1  = egp * apf;
                f32x2 t2  = __builtin_elementwise_fma(cp2[tt][r], p1, t1);
                f32x2 cn  = t2 * R_;                              // scaled cell state
                cp2[tt][r] = cn;
                f32x2 ec  = {fex2(cn.x), fex2(cn.y)};             // e^{-2c}
                f32x2 Dh  = (one + eo) * (one + ec);
                f32x2 Rh  = {frcp(Dh.x), frcp(Dh.y)};
                f32x2 hh  = (one - ec) * Rh;
                ((unsigned int*)hwr)[woff + tt * 320 + r * 20] = pk2(hh.x, hh.y);
            }
        }
    };

    for (int S = 0; S < 35; ++S) {
        const int t0 = 2 * (S - wv);          // wave-uniform
        if (t0 >= 0 && t0 <= 62) {
            const int p  = S & 1;
            const int pb = p ^ 1;
            short*       Lc0 = hb + ((wv * 2 + p ) * 2    ) * 1280;  // own layer, cur parity, slot0
            short*       Lc1 = Lc0 + 1280;                            // slot1
            const short* Lp1 = hb + ((wv * 2 + pb) * 2 + 1) * 1280;  // own layer, prev parity, slot1
            const int    lb  = (wv > 0) ? (wv - 1) : 0;
            const short* Dp0 = hb + ((lb * 2 + pb) * 2    ) * 1280;  // layer below, prev parity, slot0
            const short* Dp1 = Dp0 + 1280;                            // slot1

            cell_step(t0,     Dp0, Lp1, Lc0);   // t0: input h_{l-1}(t0), recurrent h_l(t0-1)
            cell_step(t0 + 1, Dp1, Lc0, Lc1);   // t1: input h_{l-1}(t1), recurrent h_l(t0)
        }
        __syncthreads();
    }

    // output head: h3(t=63) -> S=34, p=0, slot1
    if (tid < 32) {
        const short* h3 = hb + ((3 * 2 + 0) * 2 + 1) * 1280;
        float s = blin[0];
#pragma unroll
        for (int k = 0; k < 32; ++k)
            s += Wlin[k] * b2f((unsigned short)h3[tid * 40 + k]);
        out[row0 + tid] = frcp(1.0f + fex2(s * NLOG2E));
    }
}

extern "C" void kernel_launch(void* const* d_in, const int* in_sizes, int n_in,
                              void* d_out, int out_size, void* d_ws, size_t ws_size,
                              hipStream_t stream) {
    const float* x    = (const float*)d_in[0];
    const float* Wih0 = (const float*)d_in[1];
    const float* Wih  = (const float*)d_in[2];
    const float* Whh  = (const float*)d_in[3];
    const float* bih  = (const float*)d_in[4];
    const float* bhh  = (const float*)d_in[5];
    const float* Wlin = (const float*)d_in[6];
    const float* blin = (const float*)d_in[7];
    float* out = (float*)d_out;

    lstm_mfma<<<512, 256, 0, stream>>>(x, Wih0, Wih, Whh, bih, bhh, Wlin, blin, out);
}